// Round 7
// baseline (835.991 us; speedup 1.0000x reference)
//
#include <hip/hip_runtime.h>

// ---------------------------------------------------------------------------
// GIN block: h = MLP(x + segment_sum(x[src], dst)); MLP = Lin-ReLU-BN-Lin-ReLU-BN
// Round-6 delta: kill the CSR build. k_fill was bound by 1.25M random 4B nbr
// writes (86MB partial-line HBM write transactions, VALUBusy 0.3%) behind a
// returning atomic. Replaced {hist, scanABC, fill, gather} with:
//   k_part : bucketed counting-partition (bucket = dst>>8, 256 nodes/bucket).
//            Per-block LDS histogram -> one global atomicAdd per (block,bucket)
//            -> packed (dstLocal<<17|src) written in contiguous per-bucket runs
//            (L2 write-combined, ~10x fewer HBM write transactions).
//   k_agg  : one block per bucket; 64KB LDS acc[256][64] init from x (self
//            term folded); waves process edges 8-at-a-time (8 row loads in
//            flight) with ds_add_f32 into acc; coalesced h0 writeback.
// Rest of pipeline unchanged:
//   k_gemm<64>  : h1 = ReLU(h0 @ W1 + b1)
//   k_col_stats : BN1 stats;  k_bn_fold: fold BN1 into W2',b2'
//   k_gemm<128> : out = ReLU(h1 @ W2' + b2')
//   k_col_stats : BN2 stats;  k_bn_coeffs; k_bn_apply
// pk aliases h1's region (dead before GEMM1 writes h1).
// ---------------------------------------------------------------------------

#define NBMAX 512      // max buckets (N <= 131072)
#define CAP   8192     // edge capacity per bucket (avg 3197, sigma 57 -> safe)
#define CPB   4096     // edges per partition block

__global__ __launch_bounds__(512) void k_zero(int* __restrict__ gcnt,
                                              float* __restrict__ stats)
{
    int t = threadIdx.x;
    gcnt[t] = 0;          // NBMAX counters
    stats[t] = 0.f;       // sum1/sq1/sum2/sq2 = 512 floats
}

// Counting-partition: chunk histogram -> global reservation -> ranked write.
__global__ __launch_bounds__(256) void k_part(const int* __restrict__ ei, int E,
                                              int* __restrict__ gcnt,
                                              unsigned int* __restrict__ pk)
{
    __shared__ int cnt[NBMAX];
    __shared__ int gbase[NBMAX];
    const int tid = threadIdx.x;
    const int e0 = blockIdx.x * CPB;
    const int e1 = min(E, e0 + CPB);

    for (int i = tid; i < NBMAX; i += 256) cnt[i] = 0;
    __syncthreads();

    for (int e = e0 + tid; e < e1; e += 256)
        atomicAdd(&cnt[ei[E + e] >> 8], 1);
    __syncthreads();

    for (int i = tid; i < NBMAX; i += 256)
        gbase[i] = cnt[i] ? atomicAdd(&gcnt[i], cnt[i]) : 0;
    __syncthreads();
    for (int i = tid; i < NBMAX; i += 256) cnt[i] = 0;
    __syncthreads();

    for (int e = e0 + tid; e < e1; e += 256) {
        int dst = ei[E + e];
        int src = ei[e];                    // second pass: chunk is L2-hot
        int b = dst >> 8;
        int lr = atomicAdd(&cnt[b], 1);
        pk[(long)b * CAP + gbase[b] + lr] =
            ((unsigned)(dst & 255) << 17) | (unsigned)src;
    }
}

// One block per bucket: LDS fp32 accumulators, 8 edges in flight per wave.
__global__ __launch_bounds__(256) void k_agg(const float* __restrict__ x,
                                             const unsigned int* __restrict__ pk,
                                             const int* __restrict__ gcnt,
                                             float* __restrict__ h0, int N)
{
    __shared__ float acc[256][64];          // 64 KiB -> 2 blocks/CU
    const int tid  = threadIdx.x;
    const int lane = tid & 63;
    const int wid  = tid >> 6;
    const int node0  = blockIdx.x << 8;
    const int nNodes = min(256, N - node0);

    for (int r = wid; r < nNodes; r += 4)                 // self term
        acc[r][lane] = x[(long)(node0 + r) * 64 + lane];
    __syncthreads();

    const int cnt = gcnt[blockIdx.x];
    const unsigned int* eb = pk + (long)blockIdx.x * CAP;
    const int per = (cnt + 3) >> 2;
    const int js = wid * per;
    const int je = min(cnt, js + per);

    int j = js;
    for (; j + 8 <= je; j += 8) {
        unsigned int p[8];
        float v[8];
#pragma unroll
        for (int k = 0; k < 8; ++k) p[k] = eb[j + k];     // wave-uniform
#pragma unroll
        for (int k = 0; k < 8; ++k)                       // 8 rows in flight
            v[k] = x[(long)(p[k] & 0x1FFFFu) * 64 + lane];
#pragma unroll
        for (int k = 0; k < 8; ++k)                       // no-return ds_add
            __hip_atomic_fetch_add(&acc[p[k] >> 17][lane], v[k],
                                   __ATOMIC_RELAXED, __HIP_MEMORY_SCOPE_WORKGROUP);
    }
    for (; j < je; ++j) {
        unsigned int p = eb[j];
        float v = x[(long)(p & 0x1FFFFu) * 64 + lane];
        __hip_atomic_fetch_add(&acc[p >> 17][lane], v,
                               __ATOMIC_RELAXED, __HIP_MEMORY_SCOPE_WORKGROUP);
    }
    __syncthreads();

    for (int r = wid; r < nNodes; r += 4)
        h0[(long)(node0 + r) * 64 + lane] = acc[r][lane];
}

// Tiled fp32 GEMM: Out[N x 128] = ReLU(A[N x K] @ W[K x 128] + bias)
template<int K>
__global__ __launch_bounds__(256) void k_gemm_bias_relu(
    const float* __restrict__ A, const float* __restrict__ W,
    const float* __restrict__ bias, float* __restrict__ Out, int N)
{
    __shared__ float sAT[64][72];    // [k][row], pad 72 to break bank aliasing
    __shared__ float sW[64][128];    // [k][col]

    const int tid = threadIdx.x;
    const int tx = tid & 15;         // col group
    const int ty = tid >> 4;         // row group
    const int row0 = blockIdx.x * 64;

    float acc[4][8];
#pragma unroll
    for (int i = 0; i < 4; ++i)
#pragma unroll
        for (int j = 0; j < 8; ++j) acc[i][j] = 0.f;

    for (int k0 = 0; k0 < K; k0 += 64) {
#pragma unroll
        for (int ch = 0; ch < 4; ++ch) {
            int idx = ch * 256 + tid;
            int r = idx >> 4, kq = idx & 15;
            int grow = row0 + r;
            float4 v = make_float4(0.f, 0.f, 0.f, 0.f);
            if (grow < N) v = *(const float4*)(A + (long)grow * K + (k0 + kq * 4));
            sAT[kq * 4 + 0][r] = v.x;
            sAT[kq * 4 + 1][r] = v.y;
            sAT[kq * 4 + 2][r] = v.z;
            sAT[kq * 4 + 3][r] = v.w;
        }
#pragma unroll
        for (int ch = 0; ch < 8; ++ch) {
            int idx = ch * 256 + tid;
            int kr = idx >> 5, cq = idx & 31;
            *(float4*)(&sW[kr][cq * 4]) = *(const float4*)(W + (long)(k0 + kr) * 128 + cq * 4);
        }
        __syncthreads();

#pragma unroll 8
        for (int k = 0; k < 64; ++k) {
            float4 av = *(const float4*)(&sAT[k][ty * 4]);
            float4 w0 = *(const float4*)(&sW[k][tx * 4]);        // 2-way (free)
            float4 w1 = *(const float4*)(&sW[k][64 + tx * 4]);   // 2-way (free)
            float a[4] = {av.x, av.y, av.z, av.w};
            float w[8] = {w0.x, w0.y, w0.z, w0.w, w1.x, w1.y, w1.z, w1.w};
#pragma unroll
            for (int i = 0; i < 4; ++i)
#pragma unroll
                for (int j = 0; j < 8; ++j)
                    acc[i][j] = fmaf(a[i], w[j], acc[i][j]);
        }
        __syncthreads();
    }

    float b[8];
#pragma unroll
    for (int j = 0; j < 4; ++j) b[j] = bias[tx * 4 + j];
#pragma unroll
    for (int j = 0; j < 4; ++j) b[4 + j] = bias[64 + tx * 4 + j];

#pragma unroll
    for (int i = 0; i < 4; ++i) {
        int grow = row0 + ty * 4 + i;
        if (grow < N) {
            float4 o0, o1;
            o0.x = fmaxf(acc[i][0] + b[0], 0.f);
            o0.y = fmaxf(acc[i][1] + b[1], 0.f);
            o0.z = fmaxf(acc[i][2] + b[2], 0.f);
            o0.w = fmaxf(acc[i][3] + b[3], 0.f);
            o1.x = fmaxf(acc[i][4] + b[4], 0.f);
            o1.y = fmaxf(acc[i][5] + b[5], 0.f);
            o1.z = fmaxf(acc[i][6] + b[6], 0.f);
            o1.w = fmaxf(acc[i][7] + b[7], 0.f);
            *(float4*)(Out + (long)grow * 128 + tx * 4)      = o0;
            *(float4*)(Out + (long)grow * 128 + 64 + tx * 4) = o1;
        }
    }
}

__global__ __launch_bounds__(256) void k_col_stats(const float* __restrict__ H, int N,
                                                   float* __restrict__ sums,
                                                   float* __restrict__ sqs)
{
    int c = threadIdx.x & 127;
    int half = threadIdx.x >> 7;
    float s = 0.f, q = 0.f;
    for (long r = (long)blockIdx.x * 2 + half; r < N; r += (long)gridDim.x * 2) {
        float v = H[r * 128 + c];
        s += v;
        q = fmaf(v, v, q);
    }
    __shared__ float ls[256], lq[256];
    ls[threadIdx.x] = s;
    lq[threadIdx.x] = q;
    __syncthreads();
    if (threadIdx.x < 128) {
        atomicAdd(&sums[c], ls[threadIdx.x] + ls[threadIdx.x + 128]);
        atomicAdd(&sqs[c],  lq[threadIdx.x] + lq[threadIdx.x + 128]);
    }
}

// BN1 folded into GEMM2: a = g*rsqrt(var+eps); c = beta - mean*a
__global__ void k_bn_fold(const float* __restrict__ stats,
                          const float* __restrict__ gamma, const float* __restrict__ beta,
                          const float* __restrict__ W2, const float* __restrict__ b2,
                          float* __restrict__ W2p, float* __restrict__ b2p, float invN)
{
    __shared__ float as[128], cs[128];
    int j = threadIdx.x;
    float m = stats[j] * invN;
    float v = stats[128 + j] * invN - m * m;
    float a = gamma[j] * rsqrtf(v + 1e-5f);
    float c = beta[j] - m * a;
    as[j] = a;
    cs[j] = c;
    __syncthreads();
    float bb = b2[j];
    for (int k = 0; k < 128; ++k) {
        float w = W2[k * 128 + j];
        W2p[k * 128 + j] = as[k] * w;
        bb = fmaf(cs[k], w, bb);
    }
    b2p[j] = bb;
}

__global__ void k_bn_coeffs(const float* __restrict__ stats,
                            const float* __restrict__ gamma, const float* __restrict__ beta,
                            float* __restrict__ ac, float invN)
{
    int j = threadIdx.x;
    float m = stats[j] * invN;
    float v = stats[128 + j] * invN - m * m;
    float a = gamma[j] * rsqrtf(v + 1e-5f);
    ac[j] = a;
    ac[128 + j] = beta[j] - m * a;
}

__global__ __launch_bounds__(256) void k_bn_apply(float* __restrict__ out,
                                                  const float* __restrict__ ac, long n4)
{
    __shared__ float sa[128], sc[128];
    if (threadIdx.x < 128) {
        sa[threadIdx.x] = ac[threadIdx.x];
        sc[threadIdx.x] = ac[128 + threadIdx.x];
    }
    __syncthreads();
    long i = (long)blockIdx.x * 256 + threadIdx.x;
    if (i < n4) {
        float4 v = ((float4*)out)[i];
        int c0 = (int)((i * 4) & 127);
        v.x = fmaf(v.x, sa[c0 + 0], sc[c0 + 0]);
        v.y = fmaf(v.y, sa[c0 + 1], sc[c0 + 1]);
        v.z = fmaf(v.z, sa[c0 + 2], sc[c0 + 2]);
        v.w = fmaf(v.w, sa[c0 + 3], sc[c0 + 3]);
        ((float4*)out)[i] = v;
    }
}

extern "C" void kernel_launch(void* const* d_in, const int* in_sizes, int n_in,
                              void* d_out, int out_size, void* d_ws, size_t ws_size,
                              hipStream_t stream)
{
    const float* x   = (const float*)d_in[0];
    const int*   ei  = (const int*)  d_in[1];
    const float* W1  = (const float*)d_in[2];
    const float* b1  = (const float*)d_in[3];
    const float* g1  = (const float*)d_in[4];
    const float* be1 = (const float*)d_in[5];
    const float* W2  = (const float*)d_in[6];
    const float* b2  = (const float*)d_in[7];
    const float* g2  = (const float*)d_in[8];
    const float* be2 = (const float*)d_in[9];
    float* out = (float*)d_out;

    const int N = in_sizes[0] / 64;   // 100000
    const int E = in_sizes[1] / 2;    // 1250000
    const int nbuckets = (N + 255) >> 8;      // 391

    // workspace layout (floats)
    float* ws    = (float*)d_ws;
    float* h0    = ws;                        // N*64
    float* h1    = h0 + (long)N * 64;         // N*128 (pk aliases this region)
    float* W2p   = h1 + (long)N * 128;        // 128*128
    float* b2p   = W2p + 128 * 128;           // 128
    float* stats = b2p + 128;                 // 512: sum1,sq1,sum2,sq2
    float* ac    = stats + 512;               // 256: a2,c2
    int*   gcnt  = (int*)(ac + 256);          // NBMAX bucket counters

    unsigned int* pk = (unsigned int*)h1;     // nbuckets*CAP packed edges (12.8MB)

    const float invN = 1.0f / (float)N;

    k_zero<<<1, 512, 0, stream>>>(gcnt, stats);

    k_part<<<(E + CPB - 1) / CPB, 256, 0, stream>>>(ei, E, gcnt, pk);

    k_agg<<<nbuckets, 256, 0, stream>>>(x, pk, gcnt, h0, N);

    int gBlocks = (N + 63) / 64;
    k_gemm_bias_relu<64><<<gBlocks, 256, 0, stream>>>(h0, W1, b1, h1, N);

    k_col_stats<<<512, 256, 0, stream>>>(h1, N, stats, stats + 128);

    k_bn_fold<<<1, 128, 0, stream>>>(stats, g1, be1, W2, b2, W2p, b2p, invN);

    k_gemm_bias_relu<128><<<gBlocks, 256, 0, stream>>>(h1, W2p, b2p, out, N);

    k_col_stats<<<512, 256, 0, stream>>>(out, N, stats + 256, stats + 384);

    k_bn_coeffs<<<1, 128, 0, stream>>>(stats + 256, g2, be2, ac, invN);

    long n4o = (long)N * 128 / 4;
    k_bn_apply<<<(int)((n4o + 255) / 256), 256, 0, stream>>>(out, ac, n4o);
}

// Round 8
// 362.399 us; speedup vs baseline: 2.3068x; 2.3068x over previous
//
#include <hip/hip_runtime.h>

// ---------------------------------------------------------------------------
// GIN block: h = MLP(x + segment_sum(x[src], dst)); MLP = Lin-ReLU-BN-Lin-ReLU-BN
// Round-7 post-mortem: k_agg (one 64KB-LDS block per bucket) was a 5.5x
// regression vs gather: 391 blocks, 12.6% occupancy, latency-bound.
// Round-8: revert to the round-6 gather (73% occupancy, ~62us measured) and
// keep only the measured-cheap k_part. k_fill's problem (1.25M random 4B
// writes -> 86MB partial-line HBM traffic) is fixed by k_csr: per-bucket
// ranked scatter into the bucket's contiguous 32KB nbr window (L2
// write-combined), built from k_part's packed output.
// Pipeline:
//   k_zero      : gcnt = 0, stats = 0
//   k_part      : bucket edges by dst>>8 -> pk[(dst&255)<<17|src] runs
//   k_csr       : per-bucket LDS hist+scan -> beg/end[node], nbr ranked
//   k_gather    : h0[n] = x[n] + sum_j x[nbr[j]]  (wave/node, 4 rows in flight)
//   k_gemm<64>  : h1 = ReLU(h0 @ W1 + b1)
//   k_col_stats : BN1 stats;  k_bn_fold: fold BN1 into W2',b2'
//   k_gemm<128> : out = ReLU(h1 @ W2' + b2')
//   k_col_stats : BN2 stats;  k_bn_coeffs; k_bn_apply
// pk/nbr/beg/end alias h1's region (dead before GEMM1 writes h1).
// ---------------------------------------------------------------------------

#define NBMAX 512      // max buckets (N <= 131072)
#define CAP   8192     // edge capacity per bucket (avg 3200, sigma 57 -> safe)
#define CPB   4096     // edges per partition block

__global__ __launch_bounds__(512) void k_zero(int* __restrict__ gcnt,
                                              float* __restrict__ stats)
{
    int t = threadIdx.x;
    gcnt[t] = 0;          // NBMAX counters
    stats[t] = 0.f;       // sum1/sq1/sum2/sq2 = 512 floats
}

// Counting-partition: chunk histogram -> global reservation -> ranked write.
// (verified correct + cheap in round 7; byte-identical here)
__global__ __launch_bounds__(256) void k_part(const int* __restrict__ ei, int E,
                                              int* __restrict__ gcnt,
                                              unsigned int* __restrict__ pk)
{
    __shared__ int cnt[NBMAX];
    __shared__ int gbase[NBMAX];
    const int tid = threadIdx.x;
    const int e0 = blockIdx.x * CPB;
    const int e1 = min(E, e0 + CPB);

    for (int i = tid; i < NBMAX; i += 256) cnt[i] = 0;
    __syncthreads();

    for (int e = e0 + tid; e < e1; e += 256)
        atomicAdd(&cnt[ei[E + e] >> 8], 1);
    __syncthreads();

    for (int i = tid; i < NBMAX; i += 256)
        gbase[i] = cnt[i] ? atomicAdd(&gcnt[i], cnt[i]) : 0;
    __syncthreads();
    for (int i = tid; i < NBMAX; i += 256) cnt[i] = 0;
    __syncthreads();

    for (int e = e0 + tid; e < e1; e += 256) {
        int dst = ei[E + e];
        int src = ei[e];                    // second pass: chunk is L2-hot
        int b = dst >> 8;
        int lr = atomicAdd(&cnt[b], 1);
        pk[(long)b * CAP + gbase[b] + lr] =
            ((unsigned)(dst & 255) << 17) | (unsigned)src;
    }
}

// Per-bucket CSR: LDS histogram of dstLocal -> LDS exclusive scan ->
// beg/end per node -> ranked scatter of src into the bucket's nbr window.
__global__ __launch_bounds__(256) void k_csr(const unsigned int* __restrict__ pk,
                                             const int* __restrict__ gcnt,
                                             int* __restrict__ nbr,
                                             int* __restrict__ beg,
                                             int* __restrict__ endq, int N)
{
    __shared__ int lcnt[256];
    __shared__ int lscan[256];
    const int tid = threadIdx.x;
    const int b = blockIdx.x;
    const int cnt = gcnt[b];
    const unsigned int* eb = pk + (long)b * CAP;

    lcnt[tid] = 0;
    __syncthreads();
    for (int j = tid; j < cnt; j += 256)
        atomicAdd(&lcnt[eb[j] >> 17], 1);
    __syncthreads();

    int v = lcnt[tid];
    lscan[tid] = v;
    __syncthreads();
    for (int off = 1; off < 256; off <<= 1) {
        int t = (tid >= off) ? lscan[tid - off] : 0;
        __syncthreads();
        lscan[tid] += t;
        __syncthreads();
    }
    int excl = lscan[tid] - v;

    int node = (b << 8) + tid;
    if (node < N) {
        beg[node]  = b * CAP + excl;
        endq[node] = b * CAP + excl + v;
    }
    lcnt[tid] = excl;          // running head per local node
    __syncthreads();

    for (int j = tid; j < cnt; j += 256) {
        unsigned int p = eb[j];
        int lr = atomicAdd(&lcnt[p >> 17], 1);
        nbr[b * CAP + lr] = (int)(p & 0x1FFFFu);   // 32KB window: L2-combined
    }
}

// wave per node; 4x16-lane groups each walk a strided quarter of the edge
// list with float4 row segments -> 4 rows in flight per wave. (round-6 proven)
__global__ __launch_bounds__(256) void k_gather(const float4* __restrict__ x4,
                                                const int* __restrict__ beg,
                                                const int* __restrict__ endq,
                                                const int* __restrict__ nbr,
                                                float4* __restrict__ h04, int N)
{
    int wid  = threadIdx.x >> 6;
    int lane = threadIdx.x & 63;
    int node = blockIdx.x * 4 + wid;
    if (node >= N) return;
    int d4 = lane & 15;                     // float4 slot within the 64-float row
    int g  = lane >> 4;                     // edge subgroup 0..3
    int b = beg[node], e = endq[node];

    float4 acc = make_float4(0.f, 0.f, 0.f, 0.f);
    if (g == 0) acc = x4[(long)node * 16 + d4];   // self term in group 0

    for (int j = b + g; j < e; j += 4) {
        int s = nbr[j];                           // 16 lanes share one address
        float4 v = x4[(long)s * 16 + d4];         // 256B coalesced row segment
        acc.x += v.x; acc.y += v.y; acc.z += v.z; acc.w += v.w;
    }

#pragma unroll
    for (int m = 16; m <= 32; m <<= 1) {
        acc.x += __shfl_xor(acc.x, m, 64);
        acc.y += __shfl_xor(acc.y, m, 64);
        acc.z += __shfl_xor(acc.z, m, 64);
        acc.w += __shfl_xor(acc.w, m, 64);
    }

    if (g == 0) h04[(long)node * 16 + d4] = acc;
}

// Tiled fp32 GEMM: Out[N x 128] = ReLU(A[N x K] @ W[K x 128] + bias)
template<int K>
__global__ __launch_bounds__(256) void k_gemm_bias_relu(
    const float* __restrict__ A, const float* __restrict__ W,
    const float* __restrict__ bias, float* __restrict__ Out, int N)
{
    __shared__ float sAT[64][72];    // [k][row], pad 72 to break bank aliasing
    __shared__ float sW[64][128];    // [k][col]

    const int tid = threadIdx.x;
    const int tx = tid & 15;         // col group
    const int ty = tid >> 4;         // row group
    const int row0 = blockIdx.x * 64;

    float acc[4][8];
#pragma unroll
    for (int i = 0; i < 4; ++i)
#pragma unroll
        for (int j = 0; j < 8; ++j) acc[i][j] = 0.f;

    for (int k0 = 0; k0 < K; k0 += 64) {
#pragma unroll
        for (int ch = 0; ch < 4; ++ch) {
            int idx = ch * 256 + tid;
            int r = idx >> 4, kq = idx & 15;
            int grow = row0 + r;
            float4 v = make_float4(0.f, 0.f, 0.f, 0.f);
            if (grow < N) v = *(const float4*)(A + (long)grow * K + (k0 + kq * 4));
            sAT[kq * 4 + 0][r] = v.x;
            sAT[kq * 4 + 1][r] = v.y;
            sAT[kq * 4 + 2][r] = v.z;
            sAT[kq * 4 + 3][r] = v.w;
        }
#pragma unroll
        for (int ch = 0; ch < 8; ++ch) {
            int idx = ch * 256 + tid;
            int kr = idx >> 5, cq = idx & 31;
            *(float4*)(&sW[kr][cq * 4]) = *(const float4*)(W + (long)(k0 + kr) * 128 + cq * 4);
        }
        __syncthreads();

#pragma unroll 8
        for (int k = 0; k < 64; ++k) {
            float4 av = *(const float4*)(&sAT[k][ty * 4]);
            float4 w0 = *(const float4*)(&sW[k][tx * 4]);        // 2-way (free)
            float4 w1 = *(const float4*)(&sW[k][64 + tx * 4]);   // 2-way (free)
            float a[4] = {av.x, av.y, av.z, av.w};
            float w[8] = {w0.x, w0.y, w0.z, w0.w, w1.x, w1.y, w1.z, w1.w};
#pragma unroll
            for (int i = 0; i < 4; ++i)
#pragma unroll
                for (int j = 0; j < 8; ++j)
                    acc[i][j] = fmaf(a[i], w[j], acc[i][j]);
        }
        __syncthreads();
    }

    float b[8];
#pragma unroll
    for (int j = 0; j < 4; ++j) b[j] = bias[tx * 4 + j];
#pragma unroll
    for (int j = 0; j < 4; ++j) b[4 + j] = bias[64 + tx * 4 + j];

#pragma unroll
    for (int i = 0; i < 4; ++i) {
        int grow = row0 + ty * 4 + i;
        if (grow < N) {
            float4 o0, o1;
            o0.x = fmaxf(acc[i][0] + b[0], 0.f);
            o0.y = fmaxf(acc[i][1] + b[1], 0.f);
            o0.z = fmaxf(acc[i][2] + b[2], 0.f);
            o0.w = fmaxf(acc[i][3] + b[3], 0.f);
            o1.x = fmaxf(acc[i][4] + b[4], 0.f);
            o1.y = fmaxf(acc[i][5] + b[5], 0.f);
            o1.z = fmaxf(acc[i][6] + b[6], 0.f);
            o1.w = fmaxf(acc[i][7] + b[7], 0.f);
            *(float4*)(Out + (long)grow * 128 + tx * 4)      = o0;
            *(float4*)(Out + (long)grow * 128 + 64 + tx * 4) = o1;
        }
    }
}

__global__ __launch_bounds__(256) void k_col_stats(const float* __restrict__ H, int N,
                                                   float* __restrict__ sums,
                                                   float* __restrict__ sqs)
{
    int c = threadIdx.x & 127;
    int half = threadIdx.x >> 7;
    float s = 0.f, q = 0.f;
    for (long r = (long)blockIdx.x * 2 + half; r < N; r += (long)gridDim.x * 2) {
        float v = H[r * 128 + c];
        s += v;
        q = fmaf(v, v, q);
    }
    __shared__ float ls[256], lq[256];
    ls[threadIdx.x] = s;
    lq[threadIdx.x] = q;
    __syncthreads();
    if (threadIdx.x < 128) {
        atomicAdd(&sums[c], ls[threadIdx.x] + ls[threadIdx.x + 128]);
        atomicAdd(&sqs[c],  lq[threadIdx.x] + lq[threadIdx.x + 128]);
    }
}

// BN1 folded into GEMM2: a = g*rsqrt(var+eps); c = beta - mean*a
__global__ void k_bn_fold(const float* __restrict__ stats,
                          const float* __restrict__ gamma, const float* __restrict__ beta,
                          const float* __restrict__ W2, const float* __restrict__ b2,
                          float* __restrict__ W2p, float* __restrict__ b2p, float invN)
{
    __shared__ float as[128], cs[128];
    int j = threadIdx.x;
    float m = stats[j] * invN;
    float v = stats[128 + j] * invN - m * m;
    float a = gamma[j] * rsqrtf(v + 1e-5f);
    float c = beta[j] - m * a;
    as[j] = a;
    cs[j] = c;
    __syncthreads();
    float bb = b2[j];
    for (int k = 0; k < 128; ++k) {
        float w = W2[k * 128 + j];
        W2p[k * 128 + j] = as[k] * w;
        bb = fmaf(cs[k], w, bb);
    }
    b2p[j] = bb;
}

__global__ void k_bn_coeffs(const float* __restrict__ stats,
                            const float* __restrict__ gamma, const float* __restrict__ beta,
                            float* __restrict__ ac, float invN)
{
    int j = threadIdx.x;
    float m = stats[j] * invN;
    float v = stats[128 + j] * invN - m * m;
    float a = gamma[j] * rsqrtf(v + 1e-5f);
    ac[j] = a;
    ac[128 + j] = beta[j] - m * a;
}

__global__ __launch_bounds__(256) void k_bn_apply(float* __restrict__ out,
                                                  const float* __restrict__ ac, long n4)
{
    __shared__ float sa[128], sc[128];
    if (threadIdx.x < 128) {
        sa[threadIdx.x] = ac[threadIdx.x];
        sc[threadIdx.x] = ac[128 + threadIdx.x];
    }
    __syncthreads();
    long i = (long)blockIdx.x * 256 + threadIdx.x;
    if (i < n4) {
        float4 v = ((float4*)out)[i];
        int c0 = (int)((i * 4) & 127);
        v.x = fmaf(v.x, sa[c0 + 0], sc[c0 + 0]);
        v.y = fmaf(v.y, sa[c0 + 1], sc[c0 + 1]);
        v.z = fmaf(v.z, sa[c0 + 2], sc[c0 + 2]);
        v.w = fmaf(v.w, sa[c0 + 3], sc[c0 + 3]);
        ((float4*)out)[i] = v;
    }
}

extern "C" void kernel_launch(void* const* d_in, const int* in_sizes, int n_in,
                              void* d_out, int out_size, void* d_ws, size_t ws_size,
                              hipStream_t stream)
{
    const float* x   = (const float*)d_in[0];
    const int*   ei  = (const int*)  d_in[1];
    const float* W1  = (const float*)d_in[2];
    const float* b1  = (const float*)d_in[3];
    const float* g1  = (const float*)d_in[4];
    const float* be1 = (const float*)d_in[5];
    const float* W2  = (const float*)d_in[6];
    const float* b2  = (const float*)d_in[7];
    const float* g2  = (const float*)d_in[8];
    const float* be2 = (const float*)d_in[9];
    float* out = (float*)d_out;

    const int N = in_sizes[0] / 64;   // 100000
    const int E = in_sizes[1] / 2;    // 1250000
    const int nbuckets = (N + 255) >> 8;      // 391

    // workspace layout (floats)
    float* ws    = (float*)d_ws;
    float* h0    = ws;                        // N*64
    float* h1    = h0 + (long)N * 64;         // N*128 (graph arrays alias this)
    float* W2p   = h1 + (long)N * 128;        // 128*128
    float* b2p   = W2p + 128 * 128;           // 128
    float* stats = b2p + 128;                 // 512: sum1,sq1,sum2,sq2
    float* ac    = stats + 512;               // 256: a2,c2
    int*   gcnt  = (int*)(ac + 256);          // NBMAX bucket counters

    // graph arrays alias h1 (dead before GEMM1 writes h1):
    unsigned int* pk  = (unsigned int*)h1;            // nbuckets*CAP (12.8MB)
    int*          nbr = (int*)h1 + (long)NBMAX * CAP; // nbuckets*CAP (12.8MB)
    int*          beg = nbr + (long)NBMAX * CAP;      // N
    int*          endq = beg + N;                     // N

    const float invN = 1.0f / (float)N;

    k_zero<<<1, 512, 0, stream>>>(gcnt, stats);

    k_part<<<(E + CPB - 1) / CPB, 256, 0, stream>>>(ei, E, gcnt, pk);

    k_csr<<<nbuckets, 256, 0, stream>>>(pk, gcnt, nbr, beg, endq, N);

    k_gather<<<(N + 3) / 4, 256, 0, stream>>>((const float4*)x, beg, endq, nbr,
                                              (float4*)h0, N);

    int gBlocks = (N + 63) / 64;
    k_gemm_bias_relu<64><<<gBlocks, 256, 0, stream>>>(h0, W1, b1, h1, N);

    k_col_stats<<<512, 256, 0, stream>>>(h1, N, stats, stats + 128);

    k_bn_fold<<<1, 128, 0, stream>>>(stats, g1, be1, W2, b2, W2p, b2p, invN);

    k_gemm_bias_relu<128><<<gBlocks, 256, 0, stream>>>(h1, W2p, b2p, out, N);

    k_col_stats<<<512, 256, 0, stream>>>(out, N, stats + 256, stats + 384);

    k_bn_coeffs<<<1, 128, 0, stream>>>(stats + 256, g2, be2, ac, invN);

    long n4o = (long)N * 128 / 4;
    k_bn_apply<<<(int)((n4o + 255) / 256), 256, 0, stream>>>(out, ac, n4o);
}

// Round 9
// 330.312 us; speedup vs baseline: 2.5309x; 1.0971x over previous
//
#include <hip/hip_runtime.h>

// ---------------------------------------------------------------------------
// GIN block: h = MLP(x + segment_sum(x[src], dst)); MLP = Lin-ReLU-BN-Lin-ReLU-BN
// Round-8 delta (GEMM): sAT transposed staging was a 16-way bank conflict
// (scalar stores, row stride 288 ≡ 0 mod 32; SQ_LDS_BANK_CONFLICT=6.0M).
// A-tile now stored ROW-major sA[64][68] with float4 staging writes
// (bank-group (r+kq)%8, balanced -> conflict-free) and the inner loop
// k-blocked by 4 (1 ds_read_b128 per row per 4 ks, 2-way = free).
// BN column stats (sum/sumsq) fused into the GEMM epilogue
// (shfl_xor(16,32) wave reduce -> LDS -> global atomicAdd), deleting both
// k_col_stats passes (2x51MB reads).
// Pipeline:
//   k_zero      : gcnt = 0, stats = 0
//   k_part      : bucket edges by dst>>8 -> pk[(dst&255)<<17|src] runs
//   k_csr       : per-bucket LDS hist+scan -> beg/end[node], nbr ranked
//   k_gather    : h0[n] = x[n] + sum_j x[nbr[j]]  (wave/node, 4 rows in flight)
//   k_gemm<64>  : h1 = ReLU(h0 @ W1 + b1) + BN1 stats
//   k_bn_fold   : fold BN1 into W2',b2'
//   k_gemm<128> : out = ReLU(h1 @ W2' + b2') + BN2 stats
//   k_bn_coeffs : a2,c2;  k_bn_apply: out = a2*out + c2
// pk/nbr/beg/end alias h1's region (dead before GEMM1 writes h1).
// ---------------------------------------------------------------------------

#define NBMAX 512      // max buckets (N <= 131072)
#define CAP   8192     // edge capacity per bucket (avg 3200, sigma 57 -> safe)
#define CPB   4096     // edges per partition block

__global__ __launch_bounds__(512) void k_zero(int* __restrict__ gcnt,
                                              float* __restrict__ stats)
{
    int t = threadIdx.x;
    gcnt[t] = 0;          // NBMAX counters
    stats[t] = 0.f;       // sum1/sq1/sum2/sq2 = 512 floats
}

// Counting-partition: chunk histogram -> global reservation -> ranked write.
__global__ __launch_bounds__(256) void k_part(const int* __restrict__ ei, int E,
                                              int* __restrict__ gcnt,
                                              unsigned int* __restrict__ pk)
{
    __shared__ int cnt[NBMAX];
    __shared__ int gbase[NBMAX];
    const int tid = threadIdx.x;
    const int e0 = blockIdx.x * CPB;
    const int e1 = min(E, e0 + CPB);

    for (int i = tid; i < NBMAX; i += 256) cnt[i] = 0;
    __syncthreads();

    for (int e = e0 + tid; e < e1; e += 256)
        atomicAdd(&cnt[ei[E + e] >> 8], 1);
    __syncthreads();

    for (int i = tid; i < NBMAX; i += 256)
        gbase[i] = cnt[i] ? atomicAdd(&gcnt[i], cnt[i]) : 0;
    __syncthreads();
    for (int i = tid; i < NBMAX; i += 256) cnt[i] = 0;
    __syncthreads();

    for (int e = e0 + tid; e < e1; e += 256) {
        int dst = ei[E + e];
        int src = ei[e];                    // second pass: chunk is L2-hot
        int b = dst >> 8;
        int lr = atomicAdd(&cnt[b], 1);
        pk[(long)b * CAP + gbase[b] + lr] =
            ((unsigned)(dst & 255) << 17) | (unsigned)src;
    }
}

// Per-bucket CSR: LDS histogram of dstLocal -> LDS exclusive scan ->
// beg/end per node -> ranked scatter of src into the bucket's nbr window.
__global__ __launch_bounds__(256) void k_csr(const unsigned int* __restrict__ pk,
                                             const int* __restrict__ gcnt,
                                             int* __restrict__ nbr,
                                             int* __restrict__ beg,
                                             int* __restrict__ endq, int N)
{
    __shared__ int lcnt[256];
    __shared__ int lscan[256];
    const int tid = threadIdx.x;
    const int b = blockIdx.x;
    const int cnt = gcnt[b];
    const unsigned int* eb = pk + (long)b * CAP;

    lcnt[tid] = 0;
    __syncthreads();
    for (int j = tid; j < cnt; j += 256)
        atomicAdd(&lcnt[eb[j] >> 17], 1);
    __syncthreads();

    int v = lcnt[tid];
    lscan[tid] = v;
    __syncthreads();
    for (int off = 1; off < 256; off <<= 1) {
        int t = (tid >= off) ? lscan[tid - off] : 0;
        __syncthreads();
        lscan[tid] += t;
        __syncthreads();
    }
    int excl = lscan[tid] - v;

    int node = (b << 8) + tid;
    if (node < N) {
        beg[node]  = b * CAP + excl;
        endq[node] = b * CAP + excl + v;
    }
    lcnt[tid] = excl;          // running head per local node
    __syncthreads();

    for (int j = tid; j < cnt; j += 256) {
        unsigned int p = eb[j];
        int lr = atomicAdd(&lcnt[p >> 17], 1);
        nbr[b * CAP + lr] = (int)(p & 0x1FFFFu);   // 32KB window: L2-combined
    }
}

// wave per node; 4x16-lane groups each walk a strided quarter of the edge
// list with float4 row segments -> 4 rows in flight per wave.
__global__ __launch_bounds__(256) void k_gather(const float4* __restrict__ x4,
                                                const int* __restrict__ beg,
                                                const int* __restrict__ endq,
                                                const int* __restrict__ nbr,
                                                float4* __restrict__ h04, int N)
{
    int wid  = threadIdx.x >> 6;
    int lane = threadIdx.x & 63;
    int node = blockIdx.x * 4 + wid;
    if (node >= N) return;
    int d4 = lane & 15;                     // float4 slot within the 64-float row
    int g  = lane >> 4;                     // edge subgroup 0..3
    int b = beg[node], e = endq[node];

    float4 acc = make_float4(0.f, 0.f, 0.f, 0.f);
    if (g == 0) acc = x4[(long)node * 16 + d4];   // self term in group 0

    for (int j = b + g; j < e; j += 4) {
        int s = nbr[j];                           // 16 lanes share one address
        float4 v = x4[(long)s * 16 + d4];         // 256B coalesced row segment
        acc.x += v.x; acc.y += v.y; acc.z += v.z; acc.w += v.w;
    }

#pragma unroll
    for (int m = 16; m <= 32; m <<= 1) {
        acc.x += __shfl_xor(acc.x, m, 64);
        acc.y += __shfl_xor(acc.y, m, 64);
        acc.z += __shfl_xor(acc.z, m, 64);
        acc.w += __shfl_xor(acc.w, m, 64);
    }

    if (g == 0) h04[(long)node * 16 + d4] = acc;
}

// Tiled fp32 GEMM: Out[N x 128] = ReLU(A[N x K] @ W[K x 128] + bias),
// with fused column sum/sumsq (BN stats) accumulated into sums/sqs.
template<int K>
__global__ __launch_bounds__(256) void k_gemm_bias_relu(
    const float* __restrict__ A, const float* __restrict__ W,
    const float* __restrict__ bias, float* __restrict__ Out, int N,
    float* __restrict__ sums, float* __restrict__ sqs)
{
    __shared__ float sA[64][68];     // [row][k], pad 68: stage/read conflict-free
    __shared__ float sW[64][128];    // [k][col]
    __shared__ float lsum[128], lsq[128];

    const int tid = threadIdx.x;
    const int tx = tid & 15;         // col group
    const int ty = tid >> 4;         // row group
    const int row0 = blockIdx.x * 64;

    if (tid < 128) { lsum[tid] = 0.f; lsq[tid] = 0.f; }

    float acc[4][8];
#pragma unroll
    for (int i = 0; i < 4; ++i)
#pragma unroll
        for (int j = 0; j < 8; ++j) acc[i][j] = 0.f;

    for (int k0 = 0; k0 < K; k0 += 64) {
        // stage A tile row-major: 64 rows x 64 k (1024 float4, 4 per thread)
#pragma unroll
        for (int ch = 0; ch < 4; ++ch) {
            int idx = ch * 256 + tid;
            int r = idx >> 4, kq = idx & 15;
            int grow = row0 + r;
            float4 v = make_float4(0.f, 0.f, 0.f, 0.f);
            if (grow < N) v = *(const float4*)(A + (long)grow * K + (k0 + kq * 4));
            *(float4*)(&sA[r][kq * 4]) = v;           // bank-group (r+kq)%8: free
        }
        // stage W tile: 64 k x 128 cols (2048 float4, 8 per thread)
#pragma unroll
        for (int ch = 0; ch < 8; ++ch) {
            int idx = ch * 256 + tid;
            int kr = idx >> 5, cq = idx & 31;
            *(float4*)(&sW[kr][cq * 4]) = *(const float4*)(W + (long)(k0 + kr) * 128 + cq * 4);
        }
        __syncthreads();

#pragma unroll 4
        for (int k4 = 0; k4 < 16; ++k4) {
            float4 a0 = *(const float4*)(&sA[ty * 4 + 0][k4 * 4]);  // 2-way: free
            float4 a1 = *(const float4*)(&sA[ty * 4 + 1][k4 * 4]);
            float4 a2 = *(const float4*)(&sA[ty * 4 + 2][k4 * 4]);
            float4 a3 = *(const float4*)(&sA[ty * 4 + 3][k4 * 4]);
            float ar[4][4] = {{a0.x, a0.y, a0.z, a0.w},
                              {a1.x, a1.y, a1.z, a1.w},
                              {a2.x, a2.y, a2.z, a2.w},
                              {a3.x, a3.y, a3.z, a3.w}};
#pragma unroll
            for (int kk = 0; kk < 4; ++kk) {
                int k = k4 * 4 + kk;
                float4 w0 = *(const float4*)(&sW[k][tx * 4]);        // 2-way: free
                float4 w1 = *(const float4*)(&sW[k][64 + tx * 4]);   // 2-way: free
                float w[8] = {w0.x, w0.y, w0.z, w0.w, w1.x, w1.y, w1.z, w1.w};
#pragma unroll
                for (int i = 0; i < 4; ++i)
#pragma unroll
                    for (int j = 0; j < 8; ++j)
                        acc[i][j] = fmaf(ar[i][kk], w[j], acc[i][j]);
            }
        }
        __syncthreads();
    }

    float b[8];
#pragma unroll
    for (int j = 0; j < 4; ++j) b[j] = bias[tx * 4 + j];
#pragma unroll
    for (int j = 0; j < 4; ++j) b[4 + j] = bias[64 + tx * 4 + j];

    float s[8], q[8];
#pragma unroll
    for (int j = 0; j < 8; ++j) { s[j] = 0.f; q[j] = 0.f; }

#pragma unroll
    for (int i = 0; i < 4; ++i) {
        int grow = row0 + ty * 4 + i;
        if (grow < N) {
            float o[8];
#pragma unroll
            for (int j = 0; j < 8; ++j) {
                o[j] = fmaxf(acc[i][j] + b[j], 0.f);
                s[j] += o[j];
                q[j] = fmaf(o[j], o[j], q[j]);
            }
            float4 o0 = make_float4(o[0], o[1], o[2], o[3]);
            float4 o1 = make_float4(o[4], o[5], o[6], o[7]);
            *(float4*)(Out + (long)grow * 128 + tx * 4)      = o0;
            *(float4*)(Out + (long)grow * 128 + 64 + tx * 4) = o1;
        }
    }

    // wave-reduce the 4 row-groups (lanes ty*16+tx; xor 16,32), then LDS, then global
#pragma unroll
    for (int j = 0; j < 8; ++j) {
        s[j] += __shfl_xor(s[j], 16, 64);
        s[j] += __shfl_xor(s[j], 32, 64);
        q[j] += __shfl_xor(q[j], 16, 64);
        q[j] += __shfl_xor(q[j], 32, 64);
    }
    if ((tid & 63) < 16) {
#pragma unroll
        for (int j = 0; j < 4; ++j) {
            atomicAdd(&lsum[tx * 4 + j],      s[j]);
            atomicAdd(&lsq [tx * 4 + j],      q[j]);
            atomicAdd(&lsum[64 + tx * 4 + j], s[4 + j]);
            atomicAdd(&lsq [64 + tx * 4 + j], q[4 + j]);
        }
    }
    __syncthreads();
    if (tid < 128) {
        atomicAdd(&sums[tid], lsum[tid]);
        atomicAdd(&sqs[tid],  lsq[tid]);
    }
}

// BN1 folded into GEMM2: a = g*rsqrt(var+eps); c = beta - mean*a
__global__ void k_bn_fold(const float* __restrict__ stats,
                          const float* __restrict__ gamma, const float* __restrict__ beta,
                          const float* __restrict__ W2, const float* __restrict__ b2,
                          float* __restrict__ W2p, float* __restrict__ b2p, float invN)
{
    __shared__ float as[128], cs[128];
    int j = threadIdx.x;
    float m = stats[j] * invN;
    float v = stats[128 + j] * invN - m * m;
    float a = gamma[j] * rsqrtf(v + 1e-5f);
    float c = beta[j] - m * a;
    as[j] = a;
    cs[j] = c;
    __syncthreads();
    float bb = b2[j];
    for (int k = 0; k < 128; ++k) {
        float w = W2[k * 128 + j];
        W2p[k * 128 + j] = as[k] * w;
        bb = fmaf(cs[k], w, bb);
    }
    b2p[j] = bb;
}

__global__ void k_bn_coeffs(const float* __restrict__ stats,
                            const float* __restrict__ gamma, const float* __restrict__ beta,
                            float* __restrict__ ac, float invN)
{
    int j = threadIdx.x;
    float m = stats[j] * invN;
    float v = stats[128 + j] * invN - m * m;
    float a = gamma[j] * rsqrtf(v + 1e-5f);
    ac[j] = a;
    ac[128 + j] = beta[j] - m * a;
}

__global__ __launch_bounds__(256) void k_bn_apply(float* __restrict__ out,
                                                  const float* __restrict__ ac, long n4)
{
    __shared__ float sa[128], sc[128];
    if (threadIdx.x < 128) {
        sa[threadIdx.x] = ac[threadIdx.x];
        sc[threadIdx.x] = ac[128 + threadIdx.x];
    }
    __syncthreads();
    long i = (long)blockIdx.x * 256 + threadIdx.x;
    if (i < n4) {
        float4 v = ((float4*)out)[i];
        int c0 = (int)((i * 4) & 127);
        v.x = fmaf(v.x, sa[c0 + 0], sc[c0 + 0]);
        v.y = fmaf(v.y, sa[c0 + 1], sc[c0 + 1]);
        v.z = fmaf(v.z, sa[c0 + 2], sc[c0 + 2]);
        v.w = fmaf(v.w, sa[c0 + 3], sc[c0 + 3]);
        ((float4*)out)[i] = v;
    }
}

extern "C" void kernel_launch(void* const* d_in, const int* in_sizes, int n_in,
                              void* d_out, int out_size, void* d_ws, size_t ws_size,
                              hipStream_t stream)
{
    const float* x   = (const float*)d_in[0];
    const int*   ei  = (const int*)  d_in[1];
    const float* W1  = (const float*)d_in[2];
    const float* b1  = (const float*)d_in[3];
    const float* g1  = (const float*)d_in[4];
    const float* be1 = (const float*)d_in[5];
    const float* W2  = (const float*)d_in[6];
    const float* b2  = (const float*)d_in[7];
    const float* g2  = (const float*)d_in[8];
    const float* be2 = (const float*)d_in[9];
    float* out = (float*)d_out;

    const int N = in_sizes[0] / 64;   // 100000
    const int E = in_sizes[1] / 2;    // 1250000
    const int nbuckets = (N + 255) >> 8;      // 391

    // workspace layout (floats)
    float* ws    = (float*)d_ws;
    float* h0    = ws;                        // N*64
    float* h1    = h0 + (long)N * 64;         // N*128 (graph arrays alias this)
    float* W2p   = h1 + (long)N * 128;        // 128*128
    float* b2p   = W2p + 128 * 128;           // 128
    float* stats = b2p + 128;                 // 512: sum1,sq1,sum2,sq2
    float* ac    = stats + 512;               // 256: a2,c2
    int*   gcnt  = (int*)(ac + 256);          // NBMAX bucket counters

    // graph arrays alias h1 (dead before GEMM1 writes h1):
    unsigned int* pk  = (unsigned int*)h1;            // nbuckets*CAP (16.8MB)
    int*          nbr = (int*)h1 + (long)NBMAX * CAP; // nbuckets*CAP (16.8MB)
    int*          beg = nbr + (long)NBMAX * CAP;      // N
    int*          endq = beg + N;                     // N

    const float invN = 1.0f / (float)N;

    k_zero<<<1, 512, 0, stream>>>(gcnt, stats);

    k_part<<<(E + CPB - 1) / CPB, 256, 0, stream>>>(ei, E, gcnt, pk);

    k_csr<<<nbuckets, 256, 0, stream>>>(pk, gcnt, nbr, beg, endq, N);

    k_gather<<<(N + 3) / 4, 256, 0, stream>>>((const float4*)x, beg, endq, nbr,
                                              (float4*)h0, N);

    int gBlocks = (N + 63) / 64;
    k_gemm_bias_relu<64><<<gBlocks, 256, 0, stream>>>(h0, W1, b1, h1, N,
                                                      stats, stats + 128);

    k_bn_fold<<<1, 128, 0, stream>>>(stats, g1, be1, W2, b2, W2p, b2p, invN);

    k_gemm_bias_relu<128><<<gBlocks, 256, 0, stream>>>(h1, W2p, b2p, out, N,
                                                       stats + 256, stats + 384);

    k_bn_coeffs<<<1, 128, 0, stream>>>(stats + 256, g2, be2, ac, invN);

    long n4o = (long)N * 128 / 4;
    k_bn_apply<<<(int)((n4o + 255) / 256), 256, 0, stream>>>(out, ac, n4o);
}

// Round 10
// 321.424 us; speedup vs baseline: 2.6009x; 1.0277x over previous
//
#include <hip/hip_runtime.h>

// ---------------------------------------------------------------------------
// GIN block: h = MLP(x + segment_sum(x[src], dst)); MLP = Lin-ReLU-BN-Lin-ReLU-BN
// Round-9 delta: fp32 vector-FMA GEMMs (42 TF, 27% of fp32 peak, LDS/latency
// co-limited, no matrix pipe) replaced by split-bf16 MFMA GEMMs:
// a = a_hi + a_lo (bf16 pair), 3 passes ahi*bhi + alo*bhi + ahi*blo on
// v_mfma_f32_16x16x32_bf16 with fp32 accum -> fp32-level precision at
// matrix-core rates. W1/W2' pre-transposed+pre-split (k_wprep/k_bn_fold);
// A (h0/h1 fp32) split on the fly during LDS staging. Block 128x128, 4 waves
// (2x2), per-wave 4x4 16x16 tiles, K-step 32, padded LDS rows (80B stride,
// conflict-free, 16B aligned). Bias+ReLU+BN-stats epilogue fused as before.
// Pipeline:
//   k_zero      : gcnt = 0, stats = 0
//   k_part      : bucket edges by dst>>8 -> pk runs       (unchanged)
//   k_csr       : per-bucket CSR build                    (unchanged)
//   k_gather    : h0[n] = x[n] + sum x[nbr]               (unchanged)
//   k_wprep     : W1 -> W1^T split bf16
//   k_gemm<64>  : h1 = ReLU(h0 @ W1 + b1) + BN1 stats     (MFMA)
//   k_bn_fold   : BN1 fold -> W2'^T split bf16, b2'
//   k_gemm<128> : out = ReLU(h1 @ W2' + b2') + BN2 stats  (MFMA)
//   k_bn_coeffs : a2,c2;  k_bn_apply: out = a2*out + c2
// ---------------------------------------------------------------------------

typedef unsigned short u16;
typedef unsigned int   u32;
typedef __attribute__((ext_vector_type(8))) short  s8v;   // 8 bf16 (4 VGPRs)
typedef __attribute__((ext_vector_type(4))) float  f4v;   // 4 fp32 acc

#define NBMAX 512
#define CAP   8192
#define CPB   4096

__device__ __forceinline__ u16 f2bf(float f) {
    u32 u = __builtin_bit_cast(u32, f);
    return (u16)((u + 0x7FFFu + ((u >> 16) & 1u)) >> 16);   // RNE
}
__device__ __forceinline__ float bf2f(u16 h) {
    u32 u = ((u32)h) << 16;
    return __builtin_bit_cast(float, u);
}
__device__ __forceinline__ uint4 pk8(const u16* p) {
    uint4 r;
    r.x = (u32)p[0] | ((u32)p[1] << 16);
    r.y = (u32)p[2] | ((u32)p[3] << 16);
    r.z = (u32)p[4] | ((u32)p[5] << 16);
    r.w = (u32)p[6] | ((u32)p[7] << 16);
    return r;
}

__global__ __launch_bounds__(512) void k_zero(int* __restrict__ gcnt,
                                              float* __restrict__ stats)
{
    int t = threadIdx.x;
    gcnt[t] = 0;
    stats[t] = 0.f;
}

// Counting-partition: chunk histogram -> global reservation -> ranked write.
__global__ __launch_bounds__(256) void k_part(const int* __restrict__ ei, int E,
                                              int* __restrict__ gcnt,
                                              unsigned int* __restrict__ pk)
{
    __shared__ int cnt[NBMAX];
    __shared__ int gbase[NBMAX];
    const int tid = threadIdx.x;
    const int e0 = blockIdx.x * CPB;
    const int e1 = min(E, e0 + CPB);

    for (int i = tid; i < NBMAX; i += 256) cnt[i] = 0;
    __syncthreads();

    for (int e = e0 + tid; e < e1; e += 256)
        atomicAdd(&cnt[ei[E + e] >> 8], 1);
    __syncthreads();

    for (int i = tid; i < NBMAX; i += 256)
        gbase[i] = cnt[i] ? atomicAdd(&gcnt[i], cnt[i]) : 0;
    __syncthreads();
    for (int i = tid; i < NBMAX; i += 256) cnt[i] = 0;
    __syncthreads();

    for (int e = e0 + tid; e < e1; e += 256) {
        int dst = ei[E + e];
        int src = ei[e];
        int b = dst >> 8;
        int lr = atomicAdd(&cnt[b], 1);
        pk[(long)b * CAP + gbase[b] + lr] =
            ((unsigned)(dst & 255) << 17) | (unsigned)src;
    }
}

// Per-bucket CSR: LDS hist -> scan -> beg/end + ranked nbr scatter.
__global__ __launch_bounds__(256) void k_csr(const unsigned int* __restrict__ pk,
                                             const int* __restrict__ gcnt,
                                             int* __restrict__ nbr,
                                             int* __restrict__ beg,
                                             int* __restrict__ endq, int N)
{
    __shared__ int lcnt[256];
    __shared__ int lscan[256];
    const int tid = threadIdx.x;
    const int b = blockIdx.x;
    const int cnt = gcnt[b];
    const unsigned int* eb = pk + (long)b * CAP;

    lcnt[tid] = 0;
    __syncthreads();
    for (int j = tid; j < cnt; j += 256)
        atomicAdd(&lcnt[eb[j] >> 17], 1);
    __syncthreads();

    int v = lcnt[tid];
    lscan[tid] = v;
    __syncthreads();
    for (int off = 1; off < 256; off <<= 1) {
        int t = (tid >= off) ? lscan[tid - off] : 0;
        __syncthreads();
        lscan[tid] += t;
        __syncthreads();
    }
    int excl = lscan[tid] - v;

    int node = (b << 8) + tid;
    if (node < N) {
        beg[node]  = b * CAP + excl;
        endq[node] = b * CAP + excl + v;
    }
    lcnt[tid] = excl;
    __syncthreads();

    for (int j = tid; j < cnt; j += 256) {
        unsigned int p = eb[j];
        int lr = atomicAdd(&lcnt[p >> 17], 1);
        nbr[b * CAP + lr] = (int)(p & 0x1FFFFu);
    }
}

// wave per node; 4x16-lane groups, 4 rows in flight. (round-6 proven)
__global__ __launch_bounds__(256) void k_gather(const float4* __restrict__ x4,
                                                const int* __restrict__ beg,
                                                const int* __restrict__ endq,
                                                const int* __restrict__ nbr,
                                                float4* __restrict__ h04, int N)
{
    int wid  = threadIdx.x >> 6;
    int lane = threadIdx.x & 63;
    int node = blockIdx.x * 4 + wid;
    if (node >= N) return;
    int d4 = lane & 15;
    int g  = lane >> 4;
    int b = beg[node], e = endq[node];

    float4 acc = make_float4(0.f, 0.f, 0.f, 0.f);
    if (g == 0) acc = x4[(long)node * 16 + d4];

    for (int j = b + g; j < e; j += 4) {
        int s = nbr[j];
        float4 v = x4[(long)s * 16 + d4];
        acc.x += v.x; acc.y += v.y; acc.z += v.z; acc.w += v.w;
    }

#pragma unroll
    for (int m = 16; m <= 32; m <<= 1) {
        acc.x += __shfl_xor(acc.x, m, 64);
        acc.y += __shfl_xor(acc.y, m, 64);
        acc.z += __shfl_xor(acc.z, m, 64);
        acc.w += __shfl_xor(acc.w, m, 64);
    }

    if (g == 0) h04[(long)node * 16 + d4] = acc;
}

// W1[64][128] fp32 -> W1^T split bf16 [col][k]
__global__ void k_wprep(const float* __restrict__ W1,
                        u16* __restrict__ w1th, u16* __restrict__ w1tl)
{
    int j = threadIdx.x;             // 128 cols
    for (int k = 0; k < 64; ++k) {
        float w = W1[k * 128 + j];
        u16 h = f2bf(w);
        w1th[j * 64 + k] = h;
        w1tl[j * 64 + k] = f2bf(w - bf2f(h));
    }
}

// Split-bf16 MFMA GEMM: Out[N x 128] = ReLU(A[N x K] @ W + bias), fused BN stats.
// W given pre-transposed/pre-split: WT[col][k] bf16 hi/lo.
// Block 128 rows x 128 cols, 4 waves (2x2), per-wave 4x4 MFMA 16x16 tiles.
template<int K>
__global__ __launch_bounds__(256) void k_gemm_mfma(
    const float* __restrict__ A, const u16* __restrict__ WTh,
    const u16* __restrict__ WTl, const float* __restrict__ bias,
    float* __restrict__ Out, int N,
    float* __restrict__ sums, float* __restrict__ sqs)
{
    __shared__ u16 sAh[128][40], sAl[128][40];   // [row][k], pad->80B stride
    __shared__ u16 sBh[128][40], sBl[128][40];   // [col][k]
    __shared__ float lsum[128], lsq[128];

    const int tid  = threadIdx.x;
    const int lane = tid & 63, wid = tid >> 6;
    const int wr = wid >> 1, wc = wid & 1;
    const int cq = lane & 15, rq = lane >> 4;
    const int koff = rq * 8;
    const int row0 = blockIdx.x * 128;
    const int sr = tid >> 1;          // staging row/col 0..127
    const int hf = tid & 1;           // staging k-half

    if (tid < 128) { lsum[tid] = 0.f; lsq[tid] = 0.f; }

    f4v acc[4][4];
#pragma unroll
    for (int i = 0; i < 4; ++i)
#pragma unroll
        for (int j = 0; j < 4; ++j)
#pragma unroll
            for (int e = 0; e < 4; ++e) acc[i][j][e] = 0.f;

    for (int k0 = 0; k0 < K; k0 += 32) {
        __syncthreads();
        {   // stage A: fp32 -> hi/lo bf16
            float v[16];
            int grow = row0 + sr;
            if (grow < N) {
                const float4* src = (const float4*)(A + (long)grow * K + k0 + hf * 16);
#pragma unroll
                for (int i = 0; i < 4; ++i) {
                    float4 f = src[i];
                    v[4*i] = f.x; v[4*i+1] = f.y; v[4*i+2] = f.z; v[4*i+3] = f.w;
                }
            } else {
#pragma unroll
                for (int i = 0; i < 16; ++i) v[i] = 0.f;
            }
            u16 hh[16], ll[16];
#pragma unroll
            for (int i = 0; i < 16; ++i) {
                hh[i] = f2bf(v[i]);
                ll[i] = f2bf(v[i] - bf2f(hh[i]));
            }
            *(uint4*)&sAh[sr][hf*16]     = pk8(hh);
            *(uint4*)&sAh[sr][hf*16 + 8] = pk8(hh + 8);
            *(uint4*)&sAl[sr][hf*16]     = pk8(ll);
            *(uint4*)&sAl[sr][hf*16 + 8] = pk8(ll + 8);
        }
        {   // stage B: straight copy of pre-split WT
            const uint4* sh = (const uint4*)(WTh + (long)sr * K + k0 + hf * 16);
            const uint4* sl = (const uint4*)(WTl + (long)sr * K + k0 + hf * 16);
            *(uint4*)&sBh[sr][hf*16]     = sh[0];
            *(uint4*)&sBh[sr][hf*16 + 8] = sh[1];
            *(uint4*)&sBl[sr][hf*16]     = sl[0];
            *(uint4*)&sBl[sr][hf*16 + 8] = sl[1];
        }
        __syncthreads();

        s8v ah[4], al[4];
#pragma unroll
        for (int tr = 0; tr < 4; ++tr) {
            int rr = wr * 64 + tr * 16 + cq;
            ah[tr] = __builtin_bit_cast(s8v, *(const uint4*)&sAh[rr][koff]);
            al[tr] = __builtin_bit_cast(s8v, *(const uint4*)&sAl[rr][koff]);
        }
#pragma unroll
        for (int tc = 0; tc < 4; ++tc) {
            int cc = wc * 64 + tc * 16 + cq;
            s8v bh = __builtin_bit_cast(s8v, *(const uint4*)&sBh[cc][koff]);
            s8v bl = __builtin_bit_cast(s8v, *(const uint4*)&sBl[cc][koff]);
#pragma unroll
            for (int tr = 0; tr < 4; ++tr) {
                acc[tr][tc] = __builtin_amdgcn_mfma_f32_16x16x32_bf16(ah[tr], bh, acc[tr][tc], 0, 0, 0);
                acc[tr][tc] = __builtin_amdgcn_mfma_f32_16x16x32_bf16(al[tr], bh, acc[tr][tc], 0, 0, 0);
                acc[tr][tc] = __builtin_amdgcn_mfma_f32_16x16x32_bf16(ah[tr], bl, acc[tr][tc], 0, 0, 0);
            }
        }
    }

    // epilogue: bias + ReLU + store + fused column stats
#pragma unroll
    for (int tc = 0; tc < 4; ++tc) {
        int col = wc * 64 + tc * 16 + cq;
        float b = bias[col];
        float s = 0.f, q = 0.f;
#pragma unroll
        for (int tr = 0; tr < 4; ++tr) {
#pragma unroll
            for (int e = 0; e < 4; ++e) {
                int row = row0 + wr * 64 + tr * 16 + rq * 4 + e;
                if (row < N) {
                    float o = fmaxf(acc[tr][tc][e] + b, 0.f);
                    Out[(long)row * 128 + col] = o;
                    s += o;
                    q = fmaf(o, o, q);
                }
            }
        }
        s += __shfl_xor(s, 16, 64); s += __shfl_xor(s, 32, 64);
        q += __shfl_xor(q, 16, 64); q += __shfl_xor(q, 32, 64);
        if (lane < 16) {
            atomicAdd(&lsum[col], s);
            atomicAdd(&lsq[col],  q);
        }
    }
    __syncthreads();
    if (tid < 128) {
        atomicAdd(&sums[tid], lsum[tid]);
        atomicAdd(&sqs[tid],  lsq[tid]);
    }
}

// BN1 fold -> W2'^T split bf16 + b2'
__global__ void k_bn_fold(const float* __restrict__ stats,
                          const float* __restrict__ gamma, const float* __restrict__ beta,
                          const float* __restrict__ W2, const float* __restrict__ b2,
                          u16* __restrict__ w2th, u16* __restrict__ w2tl,
                          float* __restrict__ b2p, float invN)
{
    __shared__ float as[128], cs[128];
    int j = threadIdx.x;
    float m = stats[j] * invN;
    float v = stats[128 + j] * invN - m * m;
    float a = gamma[j] * rsqrtf(v + 1e-5f);
    float c = beta[j] - m * a;
    as[j] = a;
    cs[j] = c;
    __syncthreads();
    float bb = b2[j];
    for (int k = 0; k < 128; ++k) {
        float w  = W2[k * 128 + j];
        float wp = as[k] * w;
        u16 h = f2bf(wp);
        w2th[j * 128 + k] = h;
        w2tl[j * 128 + k] = f2bf(wp - bf2f(h));
        bb = fmaf(cs[k], w, bb);
    }
    b2p[j] = bb;
}

__global__ void k_bn_coeffs(const float* __restrict__ stats,
                            const float* __restrict__ gamma, const float* __restrict__ beta,
                            float* __restrict__ ac, float invN)
{
    int j = threadIdx.x;
    float m = stats[j] * invN;
    float v = stats[128 + j] * invN - m * m;
    float a = gamma[j] * rsqrtf(v + 1e-5f);
    ac[j] = a;
    ac[128 + j] = beta[j] - m * a;
}

__global__ __launch_bounds__(256) void k_bn_apply(float* __restrict__ out,
                                                  const float* __restrict__ ac, long n4)
{
    __shared__ float sa[128], sc[128];
    if (threadIdx.x < 128) {
        sa[threadIdx.x] = ac[threadIdx.x];
        sc[threadIdx.x] = ac[128 + threadIdx.x];
    }
    __syncthreads();
    long i = (long)blockIdx.x * 256 + threadIdx.x;
    if (i < n4) {
        float4 v = ((float4*)out)[i];
        int c0 = (int)((i * 4) & 127);
        v.x = fmaf(v.x, sa[c0 + 0], sc[c0 + 0]);
        v.y = fmaf(v.y, sa[c0 + 1], sc[c0 + 1]);
        v.z = fmaf(v.z, sa[c0 + 2], sc[c0 + 2]);
        v.w = fmaf(v.w, sa[c0 + 3], sc[c0 + 3]);
        ((float4*)out)[i] = v;
    }
}

extern "C" void kernel_launch(void* const* d_in, const int* in_sizes, int n_in,
                              void* d_out, int out_size, void* d_ws, size_t ws_size,
                              hipStream_t stream)
{
    const float* x   = (const float*)d_in[0];
    const int*   ei  = (const int*)  d_in[1];
    const float* W1  = (const float*)d_in[2];
    const float* b1  = (const float*)d_in[3];
    const float* g1  = (const float*)d_in[4];
    const float* be1 = (const float*)d_in[5];
    const float* W2  = (const float*)d_in[6];
    const float* b2  = (const float*)d_in[7];
    const float* g2  = (const float*)d_in[8];
    const float* be2 = (const float*)d_in[9];
    float* out = (float*)d_out;

    const int N = in_sizes[0] / 64;   // 100000
    const int E = in_sizes[1] / 2;    // 1250000
    const int nbuckets = (N + 255) >> 8;      // 391

    // workspace layout
    float* ws    = (float*)d_ws;
    float* h0    = ws;                        // N*64
    float* h1    = h0 + (long)N * 64;         // N*128 (graph arrays alias this)
    float* b2p   = h1 + (long)N * 128;        // 128
    float* stats = b2p + 128;                 // 512
    float* ac    = stats + 512;               // 256
    int*   gcnt  = (int*)(ac + 256);          // NBMAX
    u16*   w1th  = (u16*)(gcnt + NBMAX);      // 128*64
    u16*   w1tl  = w1th + 128 * 64;           // 128*64
    u16*   w2th  = w1tl + 128 * 64;           // 128*128
    u16*   w2tl  = w2th + 128 * 128;          // 128*128

    // graph arrays alias h1 (dead before GEMM1 writes h1):
    unsigned int* pk   = (unsigned int*)h1;
    int*          nbr  = (int*)h1 + (long)NBMAX * CAP;
    int*          beg  = nbr + (long)NBMAX * CAP;
    int*          endq = beg + N;

    const float invN = 1.0f / (float)N;

    k_zero<<<1, 512, 0, stream>>>(gcnt, stats);

    k_wprep<<<1, 128, 0, stream>>>(W1, w1th, w1tl);

    k_part<<<(E + CPB - 1) / CPB, 256, 0, stream>>>(ei, E, gcnt, pk);

    k_csr<<<nbuckets, 256, 0, stream>>>(pk, gcnt, nbr, beg, endq, N);

    k_gather<<<(N + 3) / 4, 256, 0, stream>>>((const float4*)x, beg, endq, nbr,
                                              (float4*)h0, N);

    int gB = (N + 127) / 128;
    k_gemm_mfma<64><<<gB, 256, 0, stream>>>(h0, w1th, w1tl, b1, h1, N,
                                            stats, stats + 128);

    k_bn_fold<<<1, 128, 0, stream>>>(stats, g1, be1, W2, b2, w2th, w2tl,
                                     b2p, invN);

    k_gemm_mfma<128><<<gB, 256, 0, stream>>>(h1, w2th, w2tl, b2p, out, N,
                                             stats + 256, stats + 384);

    k_bn_coeffs<<<1, 128, 0, stream>>>(stats + 256, g2, be2, ac, invN);

    long n4o = (long)N * 128 / 4;
    k_bn_apply<<<(int)((n4o + 255) / 256), 256, 0, stream>>>(out, ac, n4o);
}

// Round 11
// 309.823 us; speedup vs baseline: 2.6983x; 1.0374x over previous
//
#include <hip/hip_runtime.h>

// ---------------------------------------------------------------------------
// GIN block: h = MLP(x + segment_sum(x[src], dst)); MLP = Lin-ReLU-BN-Lin-ReLU-BN
// Round-10 delta: MFMA GEMM was barrier-serialized (4 k-steps, 8 barriers,
// MfmaUtil 5.7%, 1.7 TB/s) with 32 RNE conversions/thread/step in staging.
// Now: activations flow as packed u32 (hi_bf16<<16 | lo_bf16) produced once
// (gather / GEMM1 epilogue); GEMM staging = copy + 2-op unpack; K-step 64;
// GEMM1 = single staging phase (1 barrier); GEMM2 = 2 steps with register
// prefetch of step 1 issued before step-0 MFMA (async-split, 3 barriers).
// LDS rows padded to 72 u16 (144B stride: 16B-aligned b128, 2-way = free).
// k_bn_fold parallelized to 128 blocks (W2 fold + per-col b2' LDS reduce).
// Split-bf16 3-pass MFMA (ahi*bhi + alo*bhi + ahi*blo) keeps fp32 accuracy.
// Pipeline:
//   k_zero / k_part / k_csr / k_gather(->packed h0)   (aggregation, proven)
//   k_wprep     : W1 -> W1^T split bf16 planes
//   k_gemm<64>  : h1pk = pack(ReLU(h0 @ W1 + b1)) + BN1 stats
//   k_bn_coeffs : a1,c1
//   k_wfold     : W2'^T split planes + b2' (128 blocks)
//   k_gemm<128> : out = ReLU(h1 @ W2' + b2') fp32 + BN2 stats
//   k_bn_coeffs : a2,c2;  k_bn_apply: out = a2*out + c2
// ---------------------------------------------------------------------------

typedef unsigned short u16;
typedef unsigned int   u32;
typedef __attribute__((ext_vector_type(8))) short  s8v;   // 8 bf16 (4 VGPRs)
typedef __attribute__((ext_vector_type(4))) float  f4v;   // 4 fp32 acc

#define NBMAX 512
#define CAP   8192
#define CPB   4096

__device__ __forceinline__ u16 f2bf(float f) {
    u32 u = __builtin_bit_cast(u32, f);
    return (u16)((u + 0x7FFFu + ((u >> 16) & 1u)) >> 16);   // RNE
}
__device__ __forceinline__ float bf2f(u16 h) {
    u32 u = ((u32)h) << 16;
    return __builtin_bit_cast(float, u);
}
__device__ __forceinline__ u32 packsplit(float f) {
    u16 h = f2bf(f);
    u16 l = f2bf(f - bf2f(h));
    return ((u32)h << 16) | (u32)l;
}

__global__ __launch_bounds__(512) void k_zero(int* __restrict__ gcnt,
                                              float* __restrict__ stats)
{
    int t = threadIdx.x;
    gcnt[t] = 0;
    stats[t] = 0.f;
}

// Counting-partition: chunk histogram -> global reservation -> ranked write.
__global__ __launch_bounds__(256) void k_part(const int* __restrict__ ei, int E,
                                              int* __restrict__ gcnt,
                                              unsigned int* __restrict__ pk)
{
    __shared__ int cnt[NBMAX];
    __shared__ int gbase[NBMAX];
    const int tid = threadIdx.x;
    const int e0 = blockIdx.x * CPB;
    const int e1 = min(E, e0 + CPB);

    for (int i = tid; i < NBMAX; i += 256) cnt[i] = 0;
    __syncthreads();

    for (int e = e0 + tid; e < e1; e += 256)
        atomicAdd(&cnt[ei[E + e] >> 8], 1);
    __syncthreads();

    for (int i = tid; i < NBMAX; i += 256)
        gbase[i] = cnt[i] ? atomicAdd(&gcnt[i], cnt[i]) : 0;
    __syncthreads();
    for (int i = tid; i < NBMAX; i += 256) cnt[i] = 0;
    __syncthreads();

    for (int e = e0 + tid; e < e1; e += 256) {
        int dst = ei[E + e];
        int src = ei[e];
        int b = dst >> 8;
        int lr = atomicAdd(&cnt[b], 1);
        pk[(long)b * CAP + gbase[b] + lr] =
            ((unsigned)(dst & 255) << 17) | (unsigned)src;
    }
}

// Per-bucket CSR: LDS hist -> scan -> beg/end + ranked nbr scatter.
__global__ __launch_bounds__(256) void k_csr(const unsigned int* __restrict__ pk,
                                             const int* __restrict__ gcnt,
                                             int* __restrict__ nbr,
                                             int* __restrict__ beg,
                                             int* __restrict__ endq, int N)
{
    __shared__ int lcnt[256];
    __shared__ int lscan[256];
    const int tid = threadIdx.x;
    const int b = blockIdx.x;
    const int cnt = gcnt[b];
    const unsigned int* eb = pk + (long)b * CAP;

    lcnt[tid] = 0;
    __syncthreads();
    for (int j = tid; j < cnt; j += 256)
        atomicAdd(&lcnt[eb[j] >> 17], 1);
    __syncthreads();

    int v = lcnt[tid];
    lscan[tid] = v;
    __syncthreads();
    for (int off = 1; off < 256; off <<= 1) {
        int t = (tid >= off) ? lscan[tid - off] : 0;
        __syncthreads();
        lscan[tid] += t;
        __syncthreads();
    }
    int excl = lscan[tid] - v;

    int node = (b << 8) + tid;
    if (node < N) {
        beg[node]  = b * CAP + excl;
        endq[node] = b * CAP + excl + v;
    }
    lcnt[tid] = excl;
    __syncthreads();

    for (int j = tid; j < cnt; j += 256) {
        unsigned int p = eb[j];
        int lr = atomicAdd(&lcnt[p >> 17], 1);
        nbr[b * CAP + lr] = (int)(p & 0x1FFFFu);
    }
}

// wave per node; 4x16-lane groups, 4 rows in flight; emits PACKED u32 h0.
__global__ __launch_bounds__(256) void k_gather(const float4* __restrict__ x4,
                                                const int* __restrict__ beg,
                                                const int* __restrict__ endq,
                                                const int* __restrict__ nbr,
                                                uint4* __restrict__ h0pk, int N)
{
    int wid  = threadIdx.x >> 6;
    int lane = threadIdx.x & 63;
    int node = blockIdx.x * 4 + wid;
    if (node >= N) return;
    int d4 = lane & 15;
    int g  = lane >> 4;
    int b = beg[node], e = endq[node];

    float4 acc = make_float4(0.f, 0.f, 0.f, 0.f);
    if (g == 0) acc = x4[(long)node * 16 + d4];

    for (int j = b + g; j < e; j += 4) {
        int s = nbr[j];
        float4 v = x4[(long)s * 16 + d4];
        acc.x += v.x; acc.y += v.y; acc.z += v.z; acc.w += v.w;
    }

#pragma unroll
    for (int m = 16; m <= 32; m <<= 1) {
        acc.x += __shfl_xor(acc.x, m, 64);
        acc.y += __shfl_xor(acc.y, m, 64);
        acc.z += __shfl_xor(acc.z, m, 64);
        acc.w += __shfl_xor(acc.w, m, 64);
    }

    if (g == 0) {
        uint4 p;
        p.x = packsplit(acc.x);
        p.y = packsplit(acc.y);
        p.z = packsplit(acc.z);
        p.w = packsplit(acc.w);
        h0pk[(long)node * 16 + d4] = p;
    }
}

// W1[64][128] fp32 -> W1^T split bf16 planes [col][k]
__global__ void k_wprep(const float* __restrict__ W1,
                        u16* __restrict__ w1th, u16* __restrict__ w1tl)
{
    int j = threadIdx.x;             // 128 cols
    for (int k = 0; k < 64; ++k) {
        float w = W1[k * 128 + j];
        u16 h = f2bf(w);
        w1th[j * 64 + k] = h;
        w1tl[j * 64 + k] = f2bf(w - bf2f(h));
    }
}

// Split-bf16 MFMA GEMM, K in {64,128}, KSTEP=64.
// A: packed u32 [N][K]. W: pre-transposed split planes [128][K].
// Block 128 rows x 128 cols, 4 waves (2x2), per-wave 4x4 16x16 tiles.
// PACK=1: store packed u32 out; PACK=0: store fp32 out. Fused BN stats.
template<int K, int PACK>
__global__ __launch_bounds__(256) void k_gemm_mfma(
    const u32* __restrict__ Apk, const u16* __restrict__ WTh,
    const u16* __restrict__ WTl, const float* __restrict__ bias,
    u32* __restrict__ OutP, float* __restrict__ OutF, int N,
    float* __restrict__ sums, float* __restrict__ sqs)
{
    __shared__ u16 sAh[128][72], sAl[128][72];   // [row][k], 144B stride
    __shared__ u16 sBh[128][72], sBl[128][72];   // [col][k]
    __shared__ float lsum[128], lsq[128];

    const int tid  = threadIdx.x;
    const int lane = tid & 63, wid = tid >> 6;
    const int wr = wid >> 1, wc = wid & 1;
    const int cq = lane & 15, rq = lane >> 4;
    const int row0 = blockIdx.x * 128;
    const int sr = tid >> 1;          // staging row/col 0..127
    const int hf = tid & 1;           // k-half of the 64-wide step

    if (tid < 128) { lsum[tid] = 0.f; lsq[tid] = 0.f; }

    f4v acc[4][4];
#pragma unroll
    for (int i = 0; i < 4; ++i)
#pragma unroll
        for (int j = 0; j < 4; ++j)
#pragma unroll
            for (int e = 0; e < 4; ++e) acc[i][j][e] = 0.f;

    uint4 ar[8], brh[4], brl[4];

    // ---- load step 0 ----
    {
        int grow = row0 + sr;
        if (grow < N) {
            const uint4* ap = (const uint4*)(Apk + (long)grow * K + hf * 32);
#pragma unroll
            for (int i = 0; i < 8; ++i) ar[i] = ap[i];
        } else {
#pragma unroll
            for (int i = 0; i < 8; ++i) ar[i] = make_uint4(0, 0, 0, 0);
        }
        const uint4* bh = (const uint4*)(WTh + (long)sr * K + hf * 32);
        const uint4* bl = (const uint4*)(WTl + (long)sr * K + hf * 32);
#pragma unroll
        for (int i = 0; i < 4; ++i) { brh[i] = bh[i]; brl[i] = bl[i]; }
    }
    // ---- write step 0 to LDS ----
#pragma unroll
    for (int i = 0; i < 8; ++i) {
        int e0 = hf * 32 + i * 4;
        u32 u[4] = {ar[i].x, ar[i].y, ar[i].z, ar[i].w};
        u16 hh[4], ll[4];
#pragma unroll
        for (int t = 0; t < 4; ++t) { hh[t] = (u16)(u[t] >> 16); ll[t] = (u16)(u[t] & 0xFFFFu); }
        *(uint2*)&sAh[sr][e0] = make_uint2((u32)hh[0] | ((u32)hh[1] << 16),
                                           (u32)hh[2] | ((u32)hh[3] << 16));
        *(uint2*)&sAl[sr][e0] = make_uint2((u32)ll[0] | ((u32)ll[1] << 16),
                                           (u32)ll[2] | ((u32)ll[3] << 16));
    }
#pragma unroll
    for (int i = 0; i < 4; ++i) {
        int e0 = hf * 32 + i * 8;
        *(uint4*)&sBh[sr][e0] = brh[i];
        *(uint4*)&sBl[sr][e0] = brl[i];
    }
    __syncthreads();

    if (K == 128) {   // ---- prefetch step 1 into registers (before MFMA 0) ----
        int grow = row0 + sr;
        if (grow < N) {
            const uint4* ap = (const uint4*)(Apk + (long)grow * K + 64 + hf * 32);
#pragma unroll
            for (int i = 0; i < 8; ++i) ar[i] = ap[i];
        } else {
#pragma unroll
            for (int i = 0; i < 8; ++i) ar[i] = make_uint4(0, 0, 0, 0);
        }
        const uint4* bh = (const uint4*)(WTh + (long)sr * K + 64 + hf * 32);
        const uint4* bl = (const uint4*)(WTl + (long)sr * K + 64 + hf * 32);
#pragma unroll
        for (int i = 0; i < 4; ++i) { brh[i] = bh[i]; brl[i] = bl[i]; }
    }

    const int NSTEP = K / 64;
    for (int s = 0; s < NSTEP; ++s) {
        if (s == 1) {   // ---- write prefetched step 1 ----
            __syncthreads();   // everyone done reading step-0 LDS
#pragma unroll
            for (int i = 0; i < 8; ++i) {
                int e0 = hf * 32 + i * 4;
                u32 u[4] = {ar[i].x, ar[i].y, ar[i].z, ar[i].w};
                u16 hh[4], ll[4];
#pragma unroll
                for (int t = 0; t < 4; ++t) { hh[t] = (u16)(u[t] >> 16); ll[t] = (u16)(u[t] & 0xFFFFu); }
                *(uint2*)&sAh[sr][e0] = make_uint2((u32)hh[0] | ((u32)hh[1] << 16),
                                                   (u32)hh[2] | ((u32)hh[3] << 16));
                *(uint2*)&sAl[sr][e0] = make_uint2((u32)ll[0] | ((u32)ll[1] << 16),
                                                   (u32)ll[2] | ((u32)ll[3] << 16));
            }
#pragma unroll
            for (int i = 0; i < 4; ++i) {
                int e0 = hf * 32 + i * 8;
                *(uint4*)&sBh[sr][e0] = brh[i];
                *(uint4*)&sBl[sr][e0] = brl[i];
            }
            __syncthreads();
        }
#pragma unroll
        for (int kk = 0; kk < 2; ++kk) {
            const int koff = kk * 32 + rq * 8;
            s8v ah[4], al[4];
#pragma unroll
            for (int tr = 0; tr < 4; ++tr) {
                int rr = wr * 64 + tr * 16 + cq;
                ah[tr] = __builtin_bit_cast(s8v, *(const uint4*)&sAh[rr][koff]);
                al[tr] = __builtin_bit_cast(s8v, *(const uint4*)&sAl[rr][koff]);
            }
#pragma unroll
            for (int tc = 0; tc < 4; ++tc) {
                int cc = wc * 64 + tc * 16 + cq;
                s8v bh = __builtin_bit_cast(s8v, *(const uint4*)&sBh[cc][koff]);
                s8v bl = __builtin_bit_cast(s8v, *(const uint4*)&sBl[cc][koff]);
#pragma unroll
                for (int tr = 0; tr < 4; ++tr) {
                    acc[tr][tc] = __builtin_amdgcn_mfma_f32_16x16x32_bf16(ah[tr], bh, acc[tr][tc], 0, 0, 0);
                    acc[tr][tc] = __builtin_amdgcn_mfma_f32_16x16x32_bf16(al[tr], bh, acc[tr][tc], 0, 0, 0);
                    acc[tr][tc] = __builtin_amdgcn_mfma_f32_16x16x32_bf16(ah[tr], bl, acc[tr][tc], 0, 0, 0);
                }
            }
        }
    }

    // epilogue: bias + ReLU + store + fused column stats
#pragma unroll
    for (int tc = 0; tc < 4; ++tc) {
        int col = wc * 64 + tc * 16 + cq;
        float b = bias[col];
        float s = 0.f, q = 0.f;
#pragma unroll
        for (int tr = 0; tr < 4; ++tr) {
#pragma unroll
            for (int e = 0; e < 4; ++e) {
                int row = row0 + wr * 64 + tr * 16 + rq * 4 + e;
                if (row < N) {
                    float o = fmaxf(acc[tr][tc][e] + b, 0.f);
                    if (PACK) OutP[(long)row * 128 + col] = packsplit(o);
                    else      OutF[(long)row * 128 + col] = o;
                    s += o;
                    q = fmaf(o, o, q);
                }
            }
        }
        s += __shfl_xor(s, 16, 64); s += __shfl_xor(s, 32, 64);
        q += __shfl_xor(q, 16, 64); q += __shfl_xor(q, 32, 64);
        if (lane < 16) {
            atomicAdd(&lsum[col], s);
            atomicAdd(&lsq[col],  q);
        }
    }
    __syncthreads();
    if (tid < 128) {
        atomicAdd(&sums[tid], lsum[tid]);
        atomicAdd(&sqs[tid],  lsq[tid]);
    }
}

// BN coeffs: ac[j] = a, ac[128+j] = c
__global__ void k_bn_coeffs(const float* __restrict__ stats,
                            const float* __restrict__ gamma, const float* __restrict__ beta,
                            float* __restrict__ ac, float invN)
{
    int j = threadIdx.x;
    float m = stats[j] * invN;
    float v = stats[128 + j] * invN - m * m;
    float a = gamma[j] * rsqrtf(v + 1e-5f);
    ac[j] = a;
    ac[128 + j] = beta[j] - m * a;
}

// Fold BN1 into W2: block j (128 blocks x 128 threads), thread k:
// W2p[j][k] = split(a1[k]*W2[k][j]); b2p[j] = b2[j] + sum_k c1[k]*W2[k][j]
__global__ __launch_bounds__(128) void k_wfold(const float* __restrict__ ac1,
                                               const float* __restrict__ W2,
                                               const float* __restrict__ b2,
                                               u16* __restrict__ w2th,
                                               u16* __restrict__ w2tl,
                                               float* __restrict__ b2p)
{
    __shared__ float red[128];
    const int j = blockIdx.x;
    const int k = threadIdx.x;
    float w  = W2[k * 128 + j];
    float wp = ac1[k] * w;
    u16 h = f2bf(wp);
    w2th[j * 128 + k] = h;
    w2tl[j * 128 + k] = f2bf(wp - bf2f(h));
    red[k] = ac1[128 + k] * w;
    __syncthreads();
#pragma unroll
    for (int off = 64; off > 0; off >>= 1) {
        if (k < off) red[k] += red[k + off];
        __syncthreads();
    }
    if (k == 0) b2p[j] = b2[j] + red[0];
}

__global__ __launch_bounds__(256) void k_bn_apply(float* __restrict__ out,
                                                  const float* __restrict__ ac, long n4)
{
    __shared__ float sa[128], sc[128];
    if (threadIdx.x < 128) {
        sa[threadIdx.x] = ac[threadIdx.x];
        sc[threadIdx.x] = ac[128 + threadIdx.x];
    }
    __syncthreads();
    long i = (long)blockIdx.x * 256 + threadIdx.x;
    if (i < n4) {
        float4 v = ((float4*)out)[i];
        int c0 = (int)((i * 4) & 127);
        v.x = fmaf(v.x, sa[c0 + 0], sc[c0 + 0]);
        v.y = fmaf(v.y, sa[c0 + 1], sc[c0 + 1]);
        v.z = fmaf(v.z, sa[c0 + 2], sc[c0 + 2]);
        v.w = fmaf(v.w, sa[c0 + 3], sc[c0 + 3]);
        ((float4*)out)[i] = v;
    }
}

extern "C" void kernel_launch(void* const* d_in, const int* in_sizes, int n_in,
                              void* d_out, int out_size, void* d_ws, size_t ws_size,
                              hipStream_t stream)
{
    const float* x   = (const float*)d_in[0];
    const int*   ei  = (const int*)  d_in[1];
    const float* W1  = (const float*)d_in[2];
    const float* b1  = (const float*)d_in[3];
    const float* g1  = (const float*)d_in[4];
    const float* be1 = (const float*)d_in[5];
    const float* W2  = (const float*)d_in[6];
    const float* b2  = (const float*)d_in[7];
    const float* g2  = (const float*)d_in[8];
    const float* be2 = (const float*)d_in[9];
    float* out = (float*)d_out;

    const int N = in_sizes[0] / 64;   // 100000
    const int E = in_sizes[1] / 2;    // 1250000
    const int nbuckets = (N + 255) >> 8;      // 391

    // workspace layout
    float* ws    = (float*)d_ws;
    u32*   h0pk  = (u32*)ws;                  // N*64 packed
    u32*   h1pk  = h0pk + (long)N * 64;       // N*128 packed (graph arrays alias)
    float* b2p   = (float*)(h1pk + (long)N * 128);  // 128
    float* stats = b2p + 128;                 // 512
    float* ac1   = stats + 512;               // 256
    float* ac2   = ac1 + 256;                 // 256
    int*   gcnt  = (int*)(ac2 + 256);         // NBMAX
    u16*   w1th  = (u16*)(gcnt + NBMAX);      // 128*64
    u16*   w1tl  = w1th + 128 * 64;
    u16*   w2th  = w1tl + 128 * 64;           // 128*128
    u16*   w2tl  = w2th + 128 * 128;

    // graph arrays alias h1pk (dead before GEMM1 writes h1pk):
    unsigned int* pk   = (unsigned int*)h1pk;
    int*          nbr  = (int*)h1pk + (long)NBMAX * CAP;
    int*          beg  = nbr + (long)NBMAX * CAP;
    int*          endq = beg + N;

    const float invN = 1.0f / (float)N;

    k_zero<<<1, 512, 0, stream>>>(gcnt, stats);

    k_wprep<<<1, 128, 0, stream>>>(W1, w1th, w1tl);

    k_part<<<(E + CPB - 1) / CPB, 256, 0, stream>>>(ei, E, gcnt, pk);

    k_csr<<<nbuckets, 256, 0, stream>>>(pk, gcnt, nbr, beg, endq, N);

    k_gather<<<(N + 3) / 4, 256, 0, stream>>>((const float4*)x, beg, endq, nbr,
                                              (uint4*)h0pk, N);

    int gB = (N + 127) / 128;
    k_gemm_mfma<64, 1><<<gB, 256, 0, stream>>>(h0pk, w1th, w1tl, b1,
                                               h1pk, nullptr, N,
                                               stats, stats + 128);

    k_bn_coeffs<<<1, 128, 0, stream>>>(stats, g1, be1, ac1, invN);

    k_wfold<<<128, 128, 0, stream>>>(ac1, W2, b2, w2th, w2tl, b2p);

    k_gemm_mfma<128, 0><<<gB, 256, 0, stream>>>(h1pk, w2th, w2tl, b2p,
                                                nullptr, out, N,
                                                stats + 256, stats + 384);

    k_bn_coeffs<<<1, 128, 0, stream>>>(stats + 256, g2, be2, ac2, invN);

    long n4o = (long)N * 128 / 4;
    k_bn_apply<<<(int)((n4o + 255) / 256), 256, 0, stream>>>(out, ac2, n4o);
}